// Round 9
// baseline (154.396 us; speedup 1.0000x reference)
//
#include <hip/hip_runtime.h>

// TrigoLinear: out[b,o] = sum_i w_out[o,i]*sin(x[b,i]*w_sin[o,i]+b_sin[o,i]) + b_out[o]
// B=2048, I=256, O=512. 268M v_sin -> trans-pipe bound.
// Floor: 4096 wave-sins/SIMD * 8cy = 32.8K cy ~= 13.7us; +issue overhead ~22us.
//
// R9 thesis (from R6/R7/R8 failures): intra-wave software pipelining is
// unwinnable here (compiler collapses named-reg rotations, VGPR=36/116;
// hand vmcnt asm produced garbage twice). R8's VALUBusy arithmetic showed
// issued work is ALREADY at the ~50K cy/SIMD floor -- the whole deficit is
// stall. So: hide latency with OCCUPANCY, not pipelining.
//  - o-pair per wave -> 8192 waves = 8 waves/SIMD resident (needs VGPR<=64,
//    enforced by __launch_bounds__(256,8) and a one-chunk-live dataflow).
//    Even fully serialized {4 loads -> wait -> ~50cy compute} per chunk,
//    8 waves x 14% duty saturates the issue port.
//  - Weight record per (o-pair g, 2i-chunk c) prep-packed to 48B:
//    {a0e,a0o,a1e,a1o | c0e,c0o,c1e,c1o | w0e,w0o,w1e,w1o}, a/c pre-scaled
//    by 1/2pi -> 3 dwordx4 at imm offsets 0/16/32, one base bump per chunk.
//  - x: per-lane dwordx2 at imm offsets off a fixed row base (zero addr VALU).
//  - opq VGPR-0 keeps weight loads on the vector path (no s_load drains, R4).
//  - Block's 4 waves share one btile -> x L1 reuse; x L2 traffic ~128MB ~ 4us.
//  - All LDS/SMEM/asm-pipeline machinery deleted.

#define B_SZ 2048
#define I_SZ 256
#define O_SZ 512

typedef float f32x2 __attribute__((ext_vector_type(2)));
typedef float f32x4 __attribute__((ext_vector_type(4)));
static constexpr float kInv2Pi = 0.15915494309189535f;

static __device__ __forceinline__ f32x2 mk2(float a, float b) {
  f32x2 r; r.x = a; r.y = b; return r;
}
static __device__ __forceinline__ f32x2 lo2(f32x4 v) { return mk2(v.x, v.y); }
static __device__ __forceinline__ f32x2 hi2(f32x4 v) { return mk2(v.z, v.w); }
static __device__ __forceinline__ f32x2 fma2(f32x2 a, f32x2 b, f32x2 c) {
#if __has_builtin(__builtin_elementwise_fma)
  return __builtin_elementwise_fma(a, b, c);
#else
  return mk2(__builtin_fmaf(a.x, b.x, c.x), __builtin_fmaf(a.y, b.y, c.y));
#endif
}
static __device__ __forceinline__ f32x2 sin2(f32x2 v) {
  return mk2(__builtin_amdgcn_sinf(v.x), __builtin_amdgcn_sinf(v.y));
}

// PK[g*128 + c] = 12 floats (48B), g = o>>1, c = i-chunk of 2:
// [0:4)=a-quad {o0:even,odd | o1:even,odd}*1/2pi, [4:8)=c-quad*1/2pi, [8:12)=w-quad
__global__ __launch_bounds__(128) void prep_kernel(const float* __restrict__ w,
                                                   const float* __restrict__ bias,
                                                   float* __restrict__ PK) {
  const int o = blockIdx.x;   // 512
  const int c = threadIdx.x;  // 128
  // w[o][i][s]: float4 at 4c covers i=2c,2c+1 -> {wo_e, ws_e, wo_o, ws_o}
  const float4 wq = *reinterpret_cast<const float4*>(&w[(size_t)o * 512 + 4 * c]);
  const float b0 = bias[(size_t)o * 257 + 2 * c];
  const float b1 = bias[(size_t)o * 257 + 2 * c + 1];
  float* dst = PK + ((size_t)(o >> 1) * 128 + c) * 12 + (o & 1) * 2;
  dst[0] = wq.y * kInv2Pi;  dst[1] = wq.w * kInv2Pi;   // a (w_sin/2pi)
  dst[4] = b0 * kInv2Pi;    dst[5] = b1 * kInv2Pi;     // c (b_sin/2pi)
  dst[8] = wq.x;            dst[9] = wq.z;             // w (w_out)
}

__global__ __launch_bounds__(256, 8) void TrigoLinear_kernel(
    const float* __restrict__ x, const float* __restrict__ PK,
    const float* __restrict__ bias, float* __restrict__ out) {
  const int tid = threadIdx.x;
  const int lane = tid & 63;
  const int wave = tid >> 6;
  const int btile = blockIdx.x & 31;  // 4 waves share btile -> x L1 reuse
  const int og = blockIdx.x >> 5;     // 64 o-groups of 4 pairs
  const int g = og * 4 + wave;        // o-pair 0..255
  const int o0 = g * 2;
  const int b = btile * 64 + lane;

  // opaque lane-0: weight addresses formally divergent -> global_load (vmcnt),
  // not s_load (lgkm JIT drains, R4).
  int opq;
  asm("v_mov_b32 %0, 0" : "=v"(opq));
  const float* __restrict__ xrow = x + (size_t)b * I_SZ;
  const float* __restrict__ wp = PK + (size_t)g * (128 * 12) + opq;

  f32x2 acc0 = mk2(0.f, 0.f);
  f32x2 acc1 = mk2(0.f, 0.f);

#pragma unroll 2
  for (int c = 0; c < 128; ++c) {  // 128 chunks of 2 i
    const f32x2 xv = *reinterpret_cast<const f32x2*>(xrow + 2 * c);
    const f32x4 aq = *reinterpret_cast<const f32x4*>(wp + (size_t)c * 12);
    const f32x4 cq = *reinterpret_cast<const f32x4*>(wp + (size_t)c * 12 + 4);
    const f32x4 wq = *reinterpret_cast<const f32x4*>(wp + (size_t)c * 12 + 8);
    const f32x2 r0 = fma2(xv, lo2(aq), lo2(cq));  // o0 arg (revolutions)
    const f32x2 r1 = fma2(xv, hi2(aq), hi2(cq));  // o1 arg
    acc0 = fma2(sin2(r0), lo2(wq), acc0);
    acc1 = fma2(sin2(r1), hi2(wq), acc1);
  }

  const float bo0 = bias[(size_t)(o0 + 0) * 257 + 256];
  const float bo1 = bias[(size_t)(o0 + 1) * 257 + 256];
  f32x2 res;
  res.x = acc0.x + acc0.y + bo0;
  res.y = acc1.x + acc1.y + bo1;
  *reinterpret_cast<f32x2*>(out + (size_t)b * O_SZ + o0) = res;
}

// correctness-only fallback if ws is too small
__global__ __launch_bounds__(256) void trig_fallback(
    const float* __restrict__ x, const float* __restrict__ w,
    const float* __restrict__ bias, float* __restrict__ out) {
  const int idx = blockIdx.x * 256 + threadIdx.x;  // b*512 + o
  const int b = idx >> 9;
  const int o = idx & 511;
  float acc = bias[o * (I_SZ + 1) + I_SZ];
  for (int i = 0; i < I_SZ; ++i) {
    const float ws = w[(size_t)o * 2 * I_SZ + 2 * i + 1];
    const float wo = w[(size_t)o * 2 * I_SZ + 2 * i];
    const float bs = bias[o * (I_SZ + 1) + i];
    const float rev = __builtin_fmaf(x[(size_t)b * I_SZ + i], ws, bs) * kInv2Pi;
    acc = __builtin_fmaf(__builtin_amdgcn_sinf(rev), wo, acc);
  }
  out[idx] = acc;
}

extern "C" void kernel_launch(void* const* d_in, const int* in_sizes, int n_in,
                              void* d_out, int out_size, void* d_ws, size_t ws_size,
                              hipStream_t stream) {
  const float* x = (const float*)d_in[0];     // (2048, 256) f32
  const float* w = (const float*)d_in[1];     // (512, 256, 2) f32
  const float* bias = (const float*)d_in[2];  // (512, 257) f32
  float* out = (float*)d_out;                 // (2048, 512) f32

  const size_t need = (size_t)256 * 128 * 12 * sizeof(float);  // 1.5 MB

  if (ws_size >= need) {
    float* PK = (float*)d_ws;
    prep_kernel<<<dim3(O_SZ), dim3(128), 0, stream>>>(w, bias, PK);
    // 32 btiles x 64 o-groups = 2048 blocks = 8 blocks/CU = 8 waves/SIMD
    TrigoLinear_kernel<<<dim3(2048), dim3(256), 0, stream>>>(x, PK, bias, out);
  } else {
    trig_fallback<<<dim3(B_SZ * O_SZ / 256), dim3(256), 0, stream>>>(x, w, bias, out);
  }
}